// Round 8
// baseline (136.266 us; speedup 1.0000x reference)
//
#include <hip/hip_runtime.h>

// Fused: sigmoid(X@W+b) -> ec=E^T S, cc=colsum(S^2), ee=sum(E^2), one pass over rows.
// Tiling (r4): 256 cands over 4 blocks (cg), 16 cands/wave; single-arg
// __launch_bounds__ (r7: two-arg form clamps unified VGPR file to 256/k -> spills).
// ROUND-8: T14 prefetch rotation. r7 counters: nothing >31% busy -> latency-bound;
// per-iter the full HBM latency (~900cy) sat between load-issue and LDS-write.
// Now: prologue issues tile t0; each iter {consume regs->LDS, sync, ISSUE t+1,
// compute t}. Load latency of t+1 hides under compute of t. Same LDS, same
// barriers, +~52 VGPR live across compute (fits free allocator, no spill).

#define N_ROWS 100000
#define IN_DIM 168
#define ERR_DIM 24
#define CAND 256

#define M_TILE 64
#define NT 1563            // ceil(100000/64)
#define RBLKS 256          // row-block slots; grid = 4*RBLKS = 1024
#define XT_STRIDE 200      // 192 + 8 pad bf16
#define ST_STRIDE 72       // 64 + 8 pad bf16
#define NCOPY 8

typedef __bf16 bf16;
typedef bf16 bf16x4 __attribute__((ext_vector_type(4)));
typedef bf16 bf16x8 __attribute__((ext_vector_type(8)));
typedef float f32x4 __attribute__((ext_vector_type(4)));

// ws float layout: ec8[8][24][256] | cc8[8][256] | ee[256] ; wpack bf16 after
#define EC_F 0
#define CC_F 49152
#define EE_F 51200
#define ZERO_N 51456
#define WP_F 51712

__device__ __forceinline__ f32x4 mfma16(bf16x8 a, bf16x8 b, f32x4 c) {
    return __builtin_amdgcn_mfma_f32_16x16x32_bf16(a, b, c, 0, 0, 0);
}

__device__ __forceinline__ float fast_sigmoid(float x) {
    return __builtin_amdgcn_rcpf(1.0f + __expf(-x));
}

// Pack W[168][256] f32 -> Wpack[ct(16)][kt(6)][lane(64)][8] bf16 (B-fragment order,
// zero-padded k=168..191), and zero the ec/cc/ee accumulator region.
__global__ __launch_bounds__(256) void prep_kernel(const float* __restrict__ W,
                                                   bf16* __restrict__ wp,
                                                   float* __restrict__ zero_region) {
    int tid = blockIdx.x * 256 + threadIdx.x;   // 6144 threads total
    for (int i = tid; i < ZERO_N; i += 6144) zero_region[i] = 0.0f;
    int ct  = tid / 384;
    int rem = tid % 384;
    int kt  = rem / 64;
    int l   = rem % 64;
    int c   = ct * 16 + (l & 15);
    int k0  = kt * 32 + (l >> 4) * 8;
    bf16x8 v;
#pragma unroll
    for (int j = 0; j < 8; ++j) {
        int k = k0 + j;
        float f = (k < IN_DIM) ? W[(size_t)k * CAND + c] : 0.0f;
        v[j] = (bf16)f;
    }
    *reinterpret_cast<bf16x8*>(wp + (size_t)tid * 8) = v;
}

__global__ __launch_bounds__(256) void fused_main(const float* __restrict__ X,
                                                  const float* __restrict__ E,
                                                  const float* __restrict__ B,
                                                  const bf16* __restrict__ wp,
                                                  float* __restrict__ ec_ws,
                                                  float* __restrict__ cc_ws,
                                                  float* __restrict__ ee_ws) {
    __shared__ bf16 XT[M_TILE * XT_STRIDE];     // [row][k]   25.6 KB
    __shared__ bf16 SigT[64 * ST_STRIDE];       // [cand][row] 9.2 KB (wave-private 16-rows)
    __shared__ bf16 ET[32 * ST_STRIDE];         // [dim][row]  4.6 KB (rows 24..31 zero)
    __shared__ float red[8];

    // swizzle: pid = (rblk%8) + 8*((rblk/8) + 32*cg)  -> siblings share an XCD
    const int pid  = blockIdx.x;
    const int cg   = (pid >> 3) >> 5;                       // candidate group 0..3
    const int rblk = (((pid >> 3) & 31) << 3) | (pid & 7);  // row-block 0..255

    const int tid  = threadIdx.x;
    const int wave = tid >> 6;
    const int lane = tid & 63;
    const int lo   = lane & 15;
    const int hi   = lane >> 4;
    const int ct   = cg * 4 + wave;          // global 16-cand tile owned by this wave
    const int cand = ct * 16 + lo;           // this lane's candidate column

    // W fragments resident in registers: 6 k-frags (24 VGPR)
    bf16x8 wf[6];
#pragma unroll
    for (int kt = 0; kt < 6; ++kt)
        wf[kt] = *reinterpret_cast<const bf16x8*>(wp + (((size_t)(ct * 6 + kt)) * 64 + lane) * 8);
    const float bv = B[cand];

    f32x4 ec_acc[2];
    ec_acc[0] = (f32x4){0.f, 0.f, 0.f, 0.f};
    ec_acc[1] = (f32x4){0.f, 0.f, 0.f, 0.f};
    float cc_acc = 0.f;
    float ee_acc = 0.f;

    // one-time zeroing: ET rows 24..31, XT pad cols 168..191
    for (int i = tid; i < 8 * ST_STRIDE; i += 256)
        ET[(24 + i / ST_STRIDE) * ST_STRIDE + (i % ST_STRIDE)] = (bf16)0.0f;
    {
        bf16x4 z = {(bf16)0.f, (bf16)0.f, (bf16)0.f, (bf16)0.f};
        for (int i = tid; i < 64 * 6; i += 256) {
            int r = i / 6, p = i % 6;
            *reinterpret_cast<bf16x4*>(&XT[r * XT_STRIDE + IN_DIM + p * 4]) = z;
        }
    }

    // persistent staging registers (live across compute; prefetch pipeline)
    f32x4 xr[11], er[2];

    // issue loads for row-tile starting at row0n (masked; OOB lanes get 0)
    auto issue_tile = [&](int tn) {
        const int row0n = tn * M_TILE;
        const bool tval = (tn < NT);
#pragma unroll
        for (int j = 0; j < 11; ++j) {
            int idx = tid + j * 256;
            int r = idx / 42, c4 = idx - r * 42;
            int gr = row0n + r;
            f32x4 v = {0.f, 0.f, 0.f, 0.f};
            if (tval && idx < 2688 && gr < N_ROWS)
                v = *reinterpret_cast<const f32x4*>(X + (size_t)gr * IN_DIM + c4 * 4);
            xr[j] = v;
        }
#pragma unroll
        for (int j = 0; j < 2; ++j) {
            int idx = tid + j * 256;
            int r = idx / 6, p = idx - r * 6;
            int gr = row0n + r;
            f32x4 v = {0.f, 0.f, 0.f, 0.f};
            if (tval && idx < 384 && gr < N_ROWS)
                v = *reinterpret_cast<const f32x4*>(E + (size_t)gr * ERR_DIM + p * 4);
            er[j] = v;
        }
    };

    // ---- prologue: issue first tile ----
    issue_tile(rblk);

    for (int t = rblk; t < NT; t += RBLKS) {
        const int row0 = t * M_TILE;
        __syncthreads();   // all waves done reading LDS from previous iter

        // ---- consume previously-issued regs: convert + LDS write ----
#pragma unroll
        for (int j = 0; j < 11; ++j) {
            int idx = tid + j * 256;
            if (idx < 2688) {
                int r = idx / 42, c4 = idx - r * 42;
                f32x4 v = xr[j];
                bf16x4 pk = {(bf16)v.x, (bf16)v.y, (bf16)v.z, (bf16)v.w};
                *reinterpret_cast<bf16x4*>(&XT[r * XT_STRIDE + c4 * 4]) = pk;
            }
        }
#pragma unroll
        for (int j = 0; j < 2; ++j) {
            int idx = tid + j * 256;
            if (idx < 384) {
                int r = idx / 6, p = idx - r * 6;
                f32x4 v = er[j];
                if (cg == 0)   // ee counted once, not 4x
                    ee_acc += v.x * v.x + v.y * v.y + v.z * v.z + v.w * v.w;
                int d0 = p * 4;
                ET[(d0 + 0) * ST_STRIDE + r] = (bf16)v.x;
                ET[(d0 + 1) * ST_STRIDE + r] = (bf16)v.y;
                ET[(d0 + 2) * ST_STRIDE + r] = (bf16)v.z;
                ET[(d0 + 3) * ST_STRIDE + r] = (bf16)v.w;
            }
        }
        __syncthreads();

        // ---- PREFETCH next tile: loads in flight during compute below ----
        issue_tile(t + RBLKS);

        // --- phase A: S(64 rows x 16 cands per wave) = X @ W ---
        f32x4 acc[4];
#pragma unroll
        for (int mf = 0; mf < 4; ++mf) acc[mf] = (f32x4){0.f, 0.f, 0.f, 0.f};
#pragma unroll
        for (int kt = 0; kt < 6; ++kt) {
            bf16x8 a[4];
#pragma unroll
            for (int mf = 0; mf < 4; ++mf)
                a[mf] = *reinterpret_cast<const bf16x8*>(&XT[(mf * 16 + lo) * XT_STRIDE + kt * 32 + hi * 8]);
#pragma unroll
            for (int mf = 0; mf < 4; ++mf)
                acc[mf] = mfma16(a[mf], wf[kt], acc[mf]);
        }

        // --- bias + fast sigmoid + tail mask; cc accumulate; write SigT (wave-private) ---
#pragma unroll
        for (int mf = 0; mf < 4; ++mf) {
            const int rb = row0 + mf * 16 + hi * 4;
            f32x4 v = acc[mf];
            float s0 = fast_sigmoid(v.x + bv);
            float s1 = fast_sigmoid(v.y + bv);
            float s2 = fast_sigmoid(v.z + bv);
            float s3 = fast_sigmoid(v.w + bv);
            if (rb + 0 >= N_ROWS) s0 = 0.0f;
            if (rb + 1 >= N_ROWS) s1 = 0.0f;
            if (rb + 2 >= N_ROWS) s2 = 0.0f;
            if (rb + 3 >= N_ROWS) s3 = 0.0f;
            cc_acc += s0 * s0 + s1 * s1 + s2 * s2 + s3 * s3;
            bf16x4 pk = {(bf16)s0, (bf16)s1, (bf16)s2, (bf16)s3};
            *reinterpret_cast<bf16x4*>(&SigT[(wave * 16 + lo) * ST_STRIDE + mf * 16 + hi * 4]) = pk;
        }

        // --- phase B: ec += E^T @ S (wave-private SigT; same-wave lgkmcnt ordering) ---
#pragma unroll
        for (int kt2 = 0; kt2 < 2; ++kt2) {
            bf16x8 ea0 = *reinterpret_cast<const bf16x8*>(&ET[(0 * 16 + lo) * ST_STRIDE + kt2 * 32 + hi * 8]);
            bf16x8 ea1 = *reinterpret_cast<const bf16x8*>(&ET[(1 * 16 + lo) * ST_STRIDE + kt2 * 32 + hi * 8]);
            bf16x8 sb  = *reinterpret_cast<const bf16x8*>(&SigT[(wave * 16 + lo) * ST_STRIDE + kt2 * 32 + hi * 8]);
            ec_acc[0] = mfma16(ea0, sb, ec_acc[0]);
            ec_acc[1] = mfma16(ea1, sb, ec_acc[1]);
        }
    }

    // --- epilogue: flush partials into 8 spread copies ---
    const int copy = rblk & (NCOPY - 1);
#pragma unroll
    for (int rf = 0; rf < 2; ++rf)
#pragma unroll
        for (int rr = 0; rr < 4; ++rr) {
            int d = rf * 16 + hi * 4 + rr;
            if (d < ERR_DIM)
                atomicAdd(&ec_ws[copy * (ERR_DIM * CAND) + d * CAND + cand], ec_acc[rf][rr]);
        }
    {
        float v = cc_acc;
        v += __shfl_down(v, 32);
        v += __shfl_down(v, 16);
        if (lane < 16) atomicAdd(&cc_ws[copy * CAND + ct * 16 + lane], v);
    }
    if (cg == 0) {
#pragma unroll
        for (int off = 32; off > 0; off >>= 1) ee_acc += __shfl_down(ee_acc, off);
        if (lane == 0) red[wave] = ee_acc;
    }
    __syncthreads();
    if (cg == 0 && tid == 0) ee_ws[rblk] = red[0] + red[1] + red[2] + red[3];
}

__global__ __launch_bounds__(256) void finalize(const float* __restrict__ ec_ws,
                                                const float* __restrict__ cc_ws,
                                                const float* __restrict__ ee_ws,
                                                const float* __restrict__ r,
                                                float* __restrict__ out) {
    __shared__ float tmp[4];
    __shared__ float s_ee;
    int c = threadIdx.x;   // 0..255 = candidate
    float p = ee_ws[c];
#pragma unroll
    for (int off = 32; off > 0; off >>= 1) p += __shfl_down(p, off);
    if ((c & 63) == 0) tmp[c >> 6] = p;
    __syncthreads();
    if (c == 0) s_ee = tmp[0] + tmp[1] + tmp[2] + tmp[3];
    __syncthreads();
    float ee = s_ee;
    float ccv = 0.f;
#pragma unroll
    for (int cp = 0; cp < NCOPY; ++cp) ccv += cc_ws[cp * CAND + c];
    float left = 0.f;
#pragma unroll
    for (int d = 0; d < ERR_DIM; ++d) {
        float v = 0.f;
#pragma unroll
        for (int cp = 0; cp < NCOPY; ++cp) v += ec_ws[cp * (ERR_DIM * CAND) + d * CAND + c];
        left += v * v;
    }
    left /= ccv;
#pragma unroll
    for (int i = 0; i < 4; ++i) out[c * 4 + i] = left - (1.0f - r[i]) * ee;
}

extern "C" void kernel_launch(void* const* d_in, const int* in_sizes, int n_in,
                              void* d_out, int out_size, void* d_ws, size_t ws_size,
                              hipStream_t stream) {
    const float* X = (const float*)d_in[0];
    const float* E = (const float*)d_in[1];
    const float* W = (const float*)d_in[2];
    const float* B = (const float*)d_in[3];
    const float* r = (const float*)d_in[4];

    float* wsf   = (float*)d_ws;
    float* ec_ws = wsf + EC_F;
    float* cc_ws = wsf + CC_F;
    float* ee_ws = wsf + EE_F;
    bf16*  wp    = (bf16*)(wsf + WP_F);

    prep_kernel<<<24, 256, 0, stream>>>(W, wp, wsf);
    fused_main<<<4 * RBLKS, 256, 0, stream>>>(X, E, B, wp, ec_ws, cc_ws, ee_ws);
    finalize<<<1, 256, 0, stream>>>(ec_ws, cc_ws, ee_ws, r, (float*)d_out);
}